// Round 1
// baseline (1648.683 us; speedup 1.0000x reference)
//
#include <hip/hip_runtime.h>
#include <cstddef>

#define HD 256   // hidden dim
#define NH 28    // total head outputs (21+2+5)

// ---------------- CSR build ----------------
__global__ void hist_kernel(const int* __restrict__ dst, int* __restrict__ cnt, int E) {
    int e = blockIdx.x * blockDim.x + threadIdx.x;
    if (e < E) atomicAdd(&cnt[dst[e]], 1);
}

__global__ void chunk_reduce_kernel(const int* __restrict__ cnt, int* __restrict__ bsum, int n) {
    __shared__ int sdata[4];
    int idx = blockIdx.x * 256 + threadIdx.x;
    int v = (idx < n) ? cnt[idx] : 0;
    for (int off = 32; off > 0; off >>= 1) v += __shfl_down(v, off, 64);
    int lane = threadIdx.x & 63, wv = threadIdx.x >> 6;
    if (lane == 0) sdata[wv] = v;
    __syncthreads();
    if (threadIdx.x == 0) bsum[blockIdx.x] = sdata[0] + sdata[1] + sdata[2] + sdata[3];
}

// single block of 256 threads; nchunks <= 256
__global__ void scan_chunks_kernel(const int* __restrict__ bsum, int* __restrict__ boff,
                                   int nchunks, int* __restrict__ row_ptr_end, int E) {
    int t = threadIdx.x;
    int v = (t < nchunks) ? bsum[t] : 0;
    int lane = t & 63, wv = t >> 6;
    int incl = v;
    for (int off = 1; off < 64; off <<= 1) { int u = __shfl_up(incl, off, 64); if (lane >= off) incl += u; }
    __shared__ int wsum[4];
    if (lane == 63) wsum[wv] = incl;
    __syncthreads();
    int base = 0;
    for (int w2 = 0; w2 < 4; ++w2) if (w2 < wv) base += wsum[w2];
    if (t < nchunks) boff[t] = base + incl - v;
    if (t == 0) *row_ptr_end = E;
}

__global__ void scan_final_kernel(const int* __restrict__ cnt, const int* __restrict__ boff,
                                  int* __restrict__ row_ptr, float* __restrict__ invdeg, int n) {
    int idx = blockIdx.x * 256 + threadIdx.x;
    int v = (idx < n) ? cnt[idx] : 0;
    int lane = threadIdx.x & 63, wv = threadIdx.x >> 6;
    int incl = v;
    for (int off = 1; off < 64; off <<= 1) { int u = __shfl_up(incl, off, 64); if (lane >= off) incl += u; }
    __shared__ int wsum[4];
    if (lane == 63) wsum[wv] = incl;
    __syncthreads();
    int base = 0;
    for (int w2 = 0; w2 < 4; ++w2) if (w2 < wv) base += wsum[w2];
    if (idx < n) {
        row_ptr[idx] = boff[blockIdx.x] + base + incl - v;
        invdeg[idx] = 1.0f / fmaxf((float)v, 1.0f);
    }
}

__global__ void scatter_kernel(const int* __restrict__ src, const int* __restrict__ dst,
                               const int* __restrict__ row_ptr, int* __restrict__ cursor,
                               int* __restrict__ col_idx, int E) {
    int e = blockIdx.x * blockDim.x + threadIdx.x;
    if (e < E) {
        int d = dst[e];
        int pos = atomicAdd(&cursor[d], 1);
        col_idx[row_ptr[d] + pos] = src[e];
    }
}

// ---------------- mean aggregation (one wave per node) ----------------
__global__ void agg_mean_kernel(const float* __restrict__ H, const int* __restrict__ row_ptr,
                                const int* __restrict__ col_idx, const float* __restrict__ invdeg,
                                float* __restrict__ M, int n) {
    int wv = threadIdx.x >> 6;
    int lane = threadIdx.x & 63;
    int node = blockIdx.x * 4 + wv;
    if (node >= n) return;
    int s = row_ptr[node], e = row_ptr[node + 1];
    const float4* H4 = (const float4*)H;
    float ax = 0.f, ay = 0.f, az = 0.f, aw = 0.f;
    int i = s;
    for (; i + 4 <= e; i += 4) {
        int s0 = col_idx[i], s1 = col_idx[i + 1], s2 = col_idx[i + 2], s3 = col_idx[i + 3];
        float4 v0 = H4[s0 * 64 + lane];
        float4 v1 = H4[s1 * 64 + lane];
        float4 v2 = H4[s2 * 64 + lane];
        float4 v3 = H4[s3 * 64 + lane];
        ax += v0.x + v1.x + v2.x + v3.x;
        ay += v0.y + v1.y + v2.y + v3.y;
        az += v0.z + v1.z + v2.z + v3.z;
        aw += v0.w + v1.w + v2.w + v3.w;
    }
    for (; i < e; ++i) {
        int s0 = col_idx[i];
        float4 v = H4[s0 * 64 + lane];
        ax += v.x; ay += v.y; az += v.z; aw += v.w;
    }
    float inv = invdeg[node];
    float4 o; o.x = ax * inv; o.y = ay * inv; o.z = az * inv; o.w = aw * inv;
    ((float4*)M)[node * 64 + lane] = o;
}

// ---------------- fused dual GEMM: C = Aagg@WL^T + Aself@WR^T + bias ----------------
// 128x128 tile, 256 threads, 8x8 microtile, KC=8
#define GKC 8
#define GPAD 132
__global__ __launch_bounds__(256) void gemm256_kernel(
        const float* __restrict__ Aagg, const float* __restrict__ Aself,
        const float* __restrict__ WL, const float* __restrict__ WR,
        const float* __restrict__ bias, float* __restrict__ C, int n) {
    __shared__ float As[GKC][GPAD];
    __shared__ float Bs[GKC][GPAD];
    int t = threadIdx.x;
    int tr = t & 15, tc = t >> 4;
    int r0 = blockIdx.x * 128, c0 = blockIdx.y * 128;
    float acc[8][8];
#pragma unroll
    for (int i = 0; i < 8; ++i)
#pragma unroll
        for (int j = 0; j < 8; ++j) acc[i][j] = 0.f;

    int lr = t >> 1;            // 0..127 staging row
    int lk4 = (t & 1) * 4;      // 0 or 4

    for (int pass = 0; pass < 2; ++pass) {
        const float* A = pass ? Aself : Aagg;
        const float* W = pass ? WR : WL;
        for (int kc = 0; kc < 256; kc += GKC) {
            int gr = r0 + lr;
            float4 av = make_float4(0.f, 0.f, 0.f, 0.f);
            if (gr < n) av = *(const float4*)&A[(size_t)gr * HD + kc + lk4];
            float4 wv = *(const float4*)&W[(size_t)(c0 + lr) * HD + kc + lk4];
            As[lk4 + 0][lr] = av.x; As[lk4 + 1][lr] = av.y; As[lk4 + 2][lr] = av.z; As[lk4 + 3][lr] = av.w;
            Bs[lk4 + 0][lr] = wv.x; Bs[lk4 + 1][lr] = wv.y; Bs[lk4 + 2][lr] = wv.z; Bs[lk4 + 3][lr] = wv.w;
            __syncthreads();
#pragma unroll
            for (int kk = 0; kk < GKC; ++kk) {
                float4 a0 = *(const float4*)&As[kk][8 * tr];
                float4 a1 = *(const float4*)&As[kk][8 * tr + 4];
                float4 b0 = *(const float4*)&Bs[kk][8 * tc];
                float4 b1 = *(const float4*)&Bs[kk][8 * tc + 4];
                float a[8] = {a0.x, a0.y, a0.z, a0.w, a1.x, a1.y, a1.z, a1.w};
                float b[8] = {b0.x, b0.y, b0.z, b0.w, b1.x, b1.y, b1.z, b1.w};
#pragma unroll
                for (int i = 0; i < 8; ++i)
#pragma unroll
                    for (int j = 0; j < 8; ++j) acc[i][j] += a[i] * b[j];
            }
            __syncthreads();
        }
    }
    float bb[8];
#pragma unroll
    for (int j = 0; j < 8; ++j) bb[j] = bias[c0 + 8 * tc + j];
#pragma unroll
    for (int i = 0; i < 8; ++i) {
        int r = r0 + 8 * tr + i;
        if (r < n) {
            float4 o0, o1;
            o0.x = acc[i][0] + bb[0]; o0.y = acc[i][1] + bb[1]; o0.z = acc[i][2] + bb[2]; o0.w = acc[i][3] + bb[3];
            o1.x = acc[i][4] + bb[4]; o1.y = acc[i][5] + bb[5]; o1.z = acc[i][6] + bb[6]; o1.w = acc[i][7] + bb[7];
            float4* Crow = (float4*)&C[(size_t)r * HD + c0 + 8 * tc];
            Crow[0] = o0; Crow[1] = o1;
        }
    }
}

// ---------------- BN ----------------
__global__ void bn_stats_kernel(const float* __restrict__ Z, float* __restrict__ colsum,
                                float* __restrict__ colsumsq, int n) {
    int c = threadIdx.x;
    float s = 0.f, s2 = 0.f;
    for (int r = blockIdx.x; r < n; r += gridDim.x) {
        float v = Z[(size_t)r * HD + c];
        s += v; s2 += v * v;
    }
    atomicAdd(&colsum[c], s);
    atomicAdd(&colsumsq[c], s2);
}

__global__ void bn_finalize_kernel(const float* __restrict__ colsum, const float* __restrict__ colsumsq,
                                   const float* __restrict__ g, const float* __restrict__ bt,
                                   float* __restrict__ scale, float* __restrict__ shift, int n) {
    int c = threadIdx.x;
    float fn = (float)n;
    float mu = colsum[c] / fn;
    float var = colsumsq[c] / fn - mu * mu;
    float sc = g[c] / sqrtf(var + 1e-5f);
    scale[c] = sc;
    shift[c] = bt[c] - mu * sc;
}

__global__ void bn_apply_relu_kernel(float* __restrict__ Z, const float* __restrict__ scale,
                                     const float* __restrict__ shift, int total4) {
    int idx = blockIdx.x * blockDim.x + threadIdx.x;
    if (idx >= total4) return;
    int c = idx & 63;
    float4 z = ((float4*)Z)[idx];
    float4 sc = ((const float4*)scale)[c];
    float4 sh = ((const float4*)shift)[c];
    float4 o;
    o.x = fmaxf(z.x * sc.x + sh.x, 0.f);
    o.y = fmaxf(z.y * sc.y + sh.y, 0.f);
    o.z = fmaxf(z.z * sc.z + sh.z, 0.f);
    o.w = fmaxf(z.w * sc.w + sh.w, 0.f);
    ((float4*)Z)[idx] = o;
}

// ---------------- heads ----------------
__global__ void pack_heads_kernel(const float* __restrict__ wal, const float* __restrict__ war,
                                  const float* __restrict__ wsl, const float* __restrict__ wsr,
                                  const float* __restrict__ wel, const float* __restrict__ wer,
                                  const float* __restrict__ ba, const float* __restrict__ bs,
                                  const float* __restrict__ be,
                                  float* __restrict__ wcat, float* __restrict__ bcat) {
    int idx = blockIdx.x * blockDim.x + threadIdx.x;
    if (idx >= NH * 512) return;
    int o = idx / 512, k = idx % 512;
    const float *L, *R; int oo;
    if (o < 21)      { L = wal; R = war; oo = o; }
    else if (o < 23) { L = wsl; R = wsr; oo = o - 21; }
    else             { L = wel; R = wer; oo = o - 23; }
    float v = (k < 256) ? L[oo * 256 + k] : R[oo * 256 + (k - 256)];
    wcat[o * 512 + k] = v;
    if (k == 0) bcat[o] = (o < 21) ? ba[oo] : ((o < 23) ? bs[oo] : be[oo]);
}

// C[n,28] = [M3|h3] @ wcat^T + bcat, routed into segmented output
__global__ __launch_bounds__(256) void heads_gemm_kernel(
        const float* __restrict__ Magg, const float* __restrict__ Hself,
        const float* __restrict__ wcat, const float* __restrict__ bcat,
        float* __restrict__ out, int n) {
    __shared__ float As[16][GPAD];
    __shared__ float Bs[16][32];
    int t = threadIdx.x;
    int colg = t & 7;    // cols 4*colg .. +3
    int rowg = t >> 3;   // 0..31, rows 4*rowg .. +3
    int r0 = blockIdx.x * 128;
    float acc[4][4];
#pragma unroll
    for (int i = 0; i < 4; ++i)
#pragma unroll
        for (int j = 0; j < 4; ++j) acc[i][j] = 0.f;

    int lr = t >> 1;           // 0..127
    int lk8 = (t & 1) * 8;     // 0 or 8

    for (int kc = 0; kc < 512; kc += 16) {
        const float* A = (kc < 256) ? Magg : Hself;
        int kbase = kc & 255;
        int gr = r0 + lr;
        float4 a0 = make_float4(0.f, 0.f, 0.f, 0.f), a1 = a0;
        if (gr < n) {
            a0 = *(const float4*)&A[(size_t)gr * HD + kbase + lk8];
            a1 = *(const float4*)&A[(size_t)gr * HD + kbase + lk8 + 4];
        }
        As[lk8 + 0][lr] = a0.x; As[lk8 + 1][lr] = a0.y; As[lk8 + 2][lr] = a0.z; As[lk8 + 3][lr] = a0.w;
        As[lk8 + 4][lr] = a1.x; As[lk8 + 5][lr] = a1.y; As[lk8 + 6][lr] = a1.z; As[lk8 + 7][lr] = a1.w;
        for (int e2 = t; e2 < 512; e2 += 256) {
            int k = e2 >> 5, c = e2 & 31;
            Bs[k][c] = (c < NH) ? wcat[c * 512 + kc + k] : 0.f;
        }
        __syncthreads();
#pragma unroll
        for (int kk = 0; kk < 16; ++kk) {
            float4 a = *(const float4*)&As[kk][4 * rowg];
            float4 b = *(const float4*)&Bs[kk][4 * colg];
            float av[4] = {a.x, a.y, a.z, a.w};
            float bv[4] = {b.x, b.y, b.z, b.w};
#pragma unroll
            for (int i = 0; i < 4; ++i)
#pragma unroll
                for (int j = 0; j < 4; ++j) acc[i][j] += av[i] * bv[j];
        }
        __syncthreads();
    }
#pragma unroll
    for (int i = 0; i < 4; ++i) {
        int r = r0 + 4 * rowg + i;
        if (r >= n) continue;
#pragma unroll
        for (int j = 0; j < 4; ++j) {
            int c = 4 * colg + j;
            if (c >= NH) continue;
            float v = acc[i][j] + bcat[c];
            if (c < 21)      out[(size_t)r * 21 + c] = v;
            else if (c < 23) out[(size_t)n * 21 + (size_t)r * 2 + (c - 21)] = v;
            else             out[(size_t)n * 23 + (size_t)r * 5 + (c - 23)] = v;
        }
    }
}

// ---------------- host ----------------
static inline char* align256(char* p) {
    return (char*)(((uintptr_t)p + 255) & ~(uintptr_t)255);
}

extern "C" void kernel_launch(void* const* d_in, const int* in_sizes, int n_in,
                              void* d_out, int out_size, void* d_ws, size_t ws_size,
                              hipStream_t stream) {
    const float* x    = (const float*)d_in[0];
    const int*   esrc = (const int*)d_in[1];
    const int*   edst = (const int*)d_in[2];
    const float* w1l = (const float*)d_in[3];  const float* b1 = (const float*)d_in[4];
    const float* w1r = (const float*)d_in[5];  const float* g1 = (const float*)d_in[6];
    const float* bt1 = (const float*)d_in[7];
    const float* w2l = (const float*)d_in[8];  const float* b2 = (const float*)d_in[9];
    const float* w2r = (const float*)d_in[10]; const float* g2 = (const float*)d_in[11];
    const float* bt2 = (const float*)d_in[12];
    const float* w3l = (const float*)d_in[13]; const float* b3 = (const float*)d_in[14];
    const float* w3r = (const float*)d_in[15]; const float* g3 = (const float*)d_in[16];
    const float* bt3 = (const float*)d_in[17];
    const float* wal = (const float*)d_in[18]; const float* ba = (const float*)d_in[19];
    const float* war = (const float*)d_in[20];
    const float* wsl = (const float*)d_in[21]; const float* bs = (const float*)d_in[22];
    const float* wsr = (const float*)d_in[23];
    const float* wel = (const float*)d_in[24]; const float* be = (const float*)d_in[25];
    const float* wer = (const float*)d_in[26];
    float* out = (float*)d_out;

    int N = in_sizes[0] / HD;
    int E = in_sizes[1];

    char* p = (char*)d_ws;
    size_t NB = (size_t)N * HD * sizeof(float);
    float* bufA = (float*)p; p += NB;
    float* bufB = (float*)p; p += NB;
    float* bufC = (float*)p; p += NB;
    p = align256(p);
    int* col_idx = (int*)p; p += sizeof(int) * (size_t)E;       p = align256(p);
    int* row_ptr = (int*)p; p += sizeof(int) * (size_t)(N + 1); p = align256(p);
    int* cnt     = (int*)p; p += sizeof(int) * (size_t)N;       // cnt+cursor contiguous (one memset)
    int* cursor  = (int*)p; p += sizeof(int) * (size_t)N;       p = align256(p);
    int* bsum    = (int*)p; p += sizeof(int) * 256;
    int* boff    = (int*)p; p += sizeof(int) * 256;             p = align256(p);
    float* invdeg   = (float*)p; p += sizeof(float) * (size_t)N; p = align256(p);
    float* colsum   = (float*)p; p += sizeof(float) * 256;       // colsum+colsumsq contiguous
    float* colsumsq = (float*)p; p += sizeof(float) * 256;       p = align256(p);
    float* scale    = (float*)p; p += sizeof(float) * 256;
    float* shift    = (float*)p; p += sizeof(float) * 256;       p = align256(p);
    float* wcat     = (float*)p; p += sizeof(float) * NH * 512;  p = align256(p);
    float* bcat     = (float*)p; p += sizeof(float) * 32;
    (void)ws_size; (void)n_in; (void)out_size;

    int nchunks = (N + 255) / 256;

    // CSR build
    hipMemsetAsync(cnt, 0, sizeof(int) * 2 * (size_t)N, stream);
    hist_kernel<<<(E + 255) / 256, 256, 0, stream>>>(edst, cnt, E);
    chunk_reduce_kernel<<<nchunks, 256, 0, stream>>>(cnt, bsum, N);
    scan_chunks_kernel<<<1, 256, 0, stream>>>(bsum, boff, nchunks, &row_ptr[N], E);
    scan_final_kernel<<<nchunks, 256, 0, stream>>>(cnt, boff, row_ptr, invdeg, N);
    scatter_kernel<<<(E + 255) / 256, 256, 0, stream>>>(esrc, edst, row_ptr, cursor, col_idx, E);
    pack_heads_kernel<<<(NH * 512 + 255) / 256, 256, 0, stream>>>(wal, war, wsl, wsr, wel, wer,
                                                                  ba, bs, be, wcat, bcat);

    int aggGrid = (N + 3) / 4;
    dim3 gemmGrid((N + 127) / 128, 2);
    int total4 = N * (HD / 4);

    // ---- layer 1: h1 = bufB ----
    agg_mean_kernel<<<aggGrid, 256, 0, stream>>>(x, row_ptr, col_idx, invdeg, bufA, N);
    gemm256_kernel<<<gemmGrid, 256, 0, stream>>>(bufA, x, w1l, w1r, b1, bufB, N);
    hipMemsetAsync(colsum, 0, sizeof(float) * 512, stream);
    bn_stats_kernel<<<128, 256, 0, stream>>>(bufB, colsum, colsumsq, N);
    bn_finalize_kernel<<<1, 256, 0, stream>>>(colsum, colsumsq, g1, bt1, scale, shift, N);
    bn_apply_relu_kernel<<<(total4 + 255) / 256, 256, 0, stream>>>(bufB, scale, shift, total4);

    // ---- layer 2: h2 = bufC ----
    agg_mean_kernel<<<aggGrid, 256, 0, stream>>>(bufB, row_ptr, col_idx, invdeg, bufA, N);
    gemm256_kernel<<<gemmGrid, 256, 0, stream>>>(bufA, bufB, w2l, w2r, b2, bufC, N);
    hipMemsetAsync(colsum, 0, sizeof(float) * 512, stream);
    bn_stats_kernel<<<128, 256, 0, stream>>>(bufC, colsum, colsumsq, N);
    bn_finalize_kernel<<<1, 256, 0, stream>>>(colsum, colsumsq, g2, bt2, scale, shift, N);
    bn_apply_relu_kernel<<<(total4 + 255) / 256, 256, 0, stream>>>(bufC, scale, shift, total4);

    // ---- layer 3: h3 = bufB ----
    agg_mean_kernel<<<aggGrid, 256, 0, stream>>>(bufC, row_ptr, col_idx, invdeg, bufA, N);
    gemm256_kernel<<<gemmGrid, 256, 0, stream>>>(bufA, bufC, w3l, w3r, b3, bufB, N);
    hipMemsetAsync(colsum, 0, sizeof(float) * 512, stream);
    bn_stats_kernel<<<128, 256, 0, stream>>>(bufB, colsum, colsumsq, N);
    bn_finalize_kernel<<<1, 256, 0, stream>>>(colsum, colsumsq, g3, bt3, scale, shift, N);
    bn_apply_relu_kernel<<<(total4 + 255) / 256, 256, 0, stream>>>(bufB, scale, shift, total4);

    // ---- heads: shared aggregation of h3, then fused 28-col GEMM ----
    agg_mean_kernel<<<aggGrid, 256, 0, stream>>>(bufB, row_ptr, col_idx, invdeg, bufA, N);
    heads_gemm_kernel<<<(N + 127) / 128, 256, 0, stream>>>(bufA, bufB, wcat, bcat, out, N);
}

// Round 2
// 731.718 us; speedup vs baseline: 2.2532x; 2.2532x over previous
//
#include <hip/hip_runtime.h>
#include <hip/hip_bf16.h>
#include <cstddef>

#define HD 256   // hidden dim
#define KD 512   // concat K (mean | self)
#define NH 28    // total head outputs (21+2+5)

typedef __attribute__((ext_vector_type(8))) short bf16x8;
typedef __attribute__((ext_vector_type(4))) float f32x4;

__device__ inline float bf2f(unsigned short u) { return __uint_as_float(((unsigned)u) << 16); }
__device__ inline unsigned short f2bf(float f) {
    __hip_bfloat16 h = __float2bfloat16(f);
    return *(unsigned short*)&h;
}

// ---------------- CSR build ----------------
__global__ void hist_kernel(const int* __restrict__ dst, int* __restrict__ cnt, int E) {
    int e = blockIdx.x * blockDim.x + threadIdx.x;
    if (e < E) atomicAdd(&cnt[dst[e]], 1);
}

__global__ void chunk_reduce_kernel(const int* __restrict__ cnt, int* __restrict__ bsum, int n) {
    __shared__ int sdata[4];
    int idx = blockIdx.x * 256 + threadIdx.x;
    int v = (idx < n) ? cnt[idx] : 0;
    for (int off = 32; off > 0; off >>= 1) v += __shfl_down(v, off, 64);
    int lane = threadIdx.x & 63, wv = threadIdx.x >> 6;
    if (lane == 0) sdata[wv] = v;
    __syncthreads();
    if (threadIdx.x == 0) bsum[blockIdx.x] = sdata[0] + sdata[1] + sdata[2] + sdata[3];
}

__global__ void scan_chunks_kernel(const int* __restrict__ bsum, int* __restrict__ boff,
                                   int nchunks, int* __restrict__ row_ptr_end, int E) {
    int t = threadIdx.x;
    int v = (t < nchunks) ? bsum[t] : 0;
    int lane = t & 63, wv = t >> 6;
    int incl = v;
    for (int off = 1; off < 64; off <<= 1) { int u = __shfl_up(incl, off, 64); if (lane >= off) incl += u; }
    __shared__ int wsum[4];
    if (lane == 63) wsum[wv] = incl;
    __syncthreads();
    int base = 0;
    for (int w2 = 0; w2 < 4; ++w2) if (w2 < wv) base += wsum[w2];
    if (t < nchunks) boff[t] = base + incl - v;
    if (t == 0) *row_ptr_end = E;
}

__global__ void scan_final_kernel(const int* __restrict__ cnt, const int* __restrict__ boff,
                                  int* __restrict__ row_ptr, float* __restrict__ invdeg, int n) {
    int idx = blockIdx.x * 256 + threadIdx.x;
    int v = (idx < n) ? cnt[idx] : 0;
    int lane = threadIdx.x & 63, wv = threadIdx.x >> 6;
    int incl = v;
    for (int off = 1; off < 64; off <<= 1) { int u = __shfl_up(incl, off, 64); if (lane >= off) incl += u; }
    __shared__ int wsum[4];
    if (lane == 63) wsum[wv] = incl;
    __syncthreads();
    int base = 0;
    for (int w2 = 0; w2 < 4; ++w2) if (w2 < wv) base += wsum[w2];
    if (idx < n) {
        row_ptr[idx] = boff[blockIdx.x] + base + incl - v;
        invdeg[idx] = 1.0f / fmaxf((float)v, 1.0f);
    }
}

__global__ void scatter_kernel(const int* __restrict__ src, const int* __restrict__ dst,
                               const int* __restrict__ row_ptr, int* __restrict__ cursor,
                               int* __restrict__ col_idx, int E) {
    int e = blockIdx.x * blockDim.x + threadIdx.x;
    if (e < E) {
        int d = dst[e];
        int pos = atomicAdd(&cursor[d], 1);
        col_idx[row_ptr[d] + pos] = src[e];
    }
}

// ---------------- weight packing (fp32 -> bf16, [wl|wr] concat along K) ----------------
__global__ void pack_layer_w(const float* __restrict__ wl, const float* __restrict__ wr,
                             unsigned short* __restrict__ dst) {
    int idx = blockIdx.x * 256 + threadIdx.x;   // 256*512 total
    if (idx >= HD * KD) return;
    int nn = idx >> 9, k = idx & 511;
    float v = (k < HD) ? wl[nn * HD + k] : wr[nn * HD + (k - HD)];
    dst[idx] = f2bf(v);
}

__global__ void pack_heads(const float* __restrict__ wal, const float* __restrict__ war,
                           const float* __restrict__ wsl, const float* __restrict__ wsr,
                           const float* __restrict__ wel, const float* __restrict__ wer,
                           const float* __restrict__ ba, const float* __restrict__ bs,
                           const float* __restrict__ be,
                           unsigned short* __restrict__ wcath, float* __restrict__ bcat) {
    int idx = blockIdx.x * 256 + threadIdx.x;   // 32*512 total
    if (idx >= 32 * KD) return;
    int o = idx >> 9, k = idx & 511;
    float v = 0.f;
    if (o < 21)      { v = (k < HD) ? wal[o * HD + k] : war[o * HD + (k - HD)]; }
    else if (o < 23) { int oo = o - 21; v = (k < HD) ? wsl[oo * HD + k] : wsr[oo * HD + (k - HD)]; }
    else if (o < 28) { int oo = o - 23; v = (k < HD) ? wel[oo * HD + k] : wer[oo * HD + (k - HD)]; }
    wcath[idx] = f2bf(v);
    if (k == 0 && o < 32) {
        float b = 0.f;
        if (o < 21) b = ba[o]; else if (o < 23) b = bs[o - 21]; else if (o < 28) b = be[o - 23];
        bcat[o] = b;
    }
}

// x fp32 -> bf16 into right half of [N][512] buffer
__global__ void convert_x_kernel(const float* __restrict__ x, unsigned short* __restrict__ buf, int n) {
    int idx = blockIdx.x * 256 + threadIdx.x;   // n*64
    if (idx >= n * 64) return;
    int r = idx >> 6, c4 = (idx & 63) * 4;
    float4 v = ((const float4*)x)[idx];
    ushort4 o;
    o.x = f2bf(v.x); o.y = f2bf(v.y); o.z = f2bf(v.z); o.w = f2bf(v.w);
    *(ushort4*)&buf[(size_t)r * KD + HD + c4] = o;
}

// ---------------- mean aggregation (bf16, one wave per node) ----------------
// reads right half (self features) of buf, writes mean into left half
__global__ void agg_mean_bf16(const unsigned short* __restrict__ buf,
                              const int* __restrict__ row_ptr, const int* __restrict__ col_idx,
                              const float* __restrict__ invdeg, int n) {
    int wv = threadIdx.x >> 6;
    int lane = threadIdx.x & 63;
    int node = blockIdx.x * 4 + wv;
    if (node >= n) return;
    int s = row_ptr[node], e = row_ptr[node + 1];
    int coff = HD + lane * 4;   // right-half column offset
    float a0 = 0.f, a1 = 0.f, a2 = 0.f, a3 = 0.f;
    int i = s;
    for (; i + 4 <= e; i += 4) {
        int s0 = col_idx[i], s1 = col_idx[i + 1], s2 = col_idx[i + 2], s3 = col_idx[i + 3];
        ushort4 v0 = *(const ushort4*)&buf[(size_t)s0 * KD + coff];
        ushort4 v1 = *(const ushort4*)&buf[(size_t)s1 * KD + coff];
        ushort4 v2 = *(const ushort4*)&buf[(size_t)s2 * KD + coff];
        ushort4 v3 = *(const ushort4*)&buf[(size_t)s3 * KD + coff];
        a0 += bf2f(v0.x) + bf2f(v1.x) + bf2f(v2.x) + bf2f(v3.x);
        a1 += bf2f(v0.y) + bf2f(v1.y) + bf2f(v2.y) + bf2f(v3.y);
        a2 += bf2f(v0.z) + bf2f(v1.z) + bf2f(v2.z) + bf2f(v3.z);
        a3 += bf2f(v0.w) + bf2f(v1.w) + bf2f(v2.w) + bf2f(v3.w);
    }
    for (; i < e; ++i) {
        int s0 = col_idx[i];
        ushort4 v = *(const ushort4*)&buf[(size_t)s0 * KD + coff];
        a0 += bf2f(v.x); a1 += bf2f(v.y); a2 += bf2f(v.z); a3 += bf2f(v.w);
    }
    float inv = invdeg[node];
    ushort4 o;
    o.x = f2bf(a0 * inv); o.y = f2bf(a1 * inv); o.z = f2bf(a2 * inv); o.w = f2bf(a3 * inv);
    *(ushort4*)((unsigned short*)buf + (size_t)node * KD + lane * 4) = o;
}

// ---------------- MFMA GEMM: Z[n,256] = A[n,512](bf16) @ W[256,512]^T (bf16), fp32 out ----
// 128x128 tile, 256 threads = 4 waves (2x2), 64x64 per wave, BK=64, XOR-swizzled LDS.
#define SWIZ(row, kc) (((row) << 6) + ((((kc) ^ ((row) & 7))) << 3))

__global__ __launch_bounds__(256) void gemm_mfma(const unsigned short* __restrict__ A,
                                                 const unsigned short* __restrict__ W,
                                                 float* __restrict__ Z, int n) {
    __shared__ __align__(16) short As[128 * 64];
    __shared__ __align__(16) short Bs[128 * 64];
    int t = threadIdx.x;
    int wave = t >> 6, lane = t & 63;
    int wm = wave & 1, wn = wave >> 1;
    int lm = lane & 15, q = lane >> 4;
    int r0 = blockIdx.x * 128, c0 = blockIdx.y * 128;

    f32x4 acc[4][4];
#pragma unroll
    for (int i = 0; i < 4; ++i)
#pragma unroll
        for (int j = 0; j < 4; ++j) acc[i][j] = (f32x4){0.f, 0.f, 0.f, 0.f};

    int srow = t >> 3;     // 0..31
    int skc = t & 7;       // 8-elem chunk within BK=64

    for (int kt = 0; kt < 8; ++kt) {
        int kc = kt * 64;
#pragma unroll
        for (int u = 0; u < 4; ++u) {
            int row = srow + u * 32;
            int ga = r0 + row; if (ga >= n) ga = n - 1;
            float4 av = *(const float4*)&A[(size_t)ga * KD + kc + skc * 8];
            *(float4*)&As[SWIZ(row, skc)] = av;
            float4 wv = *(const float4*)&W[(size_t)(c0 + row) * KD + kc + skc * 8];
            *(float4*)&Bs[SWIZ(row, skc)] = wv;
        }
        __syncthreads();
#pragma unroll
        for (int kk = 0; kk < 2; ++kk) {
            bf16x8 af[4], bfv[4];
#pragma unroll
            for (int i = 0; i < 4; ++i) {
                int row = wm * 64 + i * 16 + lm;
                af[i] = *(bf16x8*)&As[SWIZ(row, kk * 4 + q)];
            }
#pragma unroll
            for (int j = 0; j < 4; ++j) {
                int row = wn * 64 + j * 16 + lm;
                bfv[j] = *(bf16x8*)&Bs[SWIZ(row, kk * 4 + q)];
            }
#pragma unroll
            for (int i = 0; i < 4; ++i)
#pragma unroll
                for (int j = 0; j < 4; ++j)
                    acc[i][j] = __builtin_amdgcn_mfma_f32_16x16x32_bf16(af[i], bfv[j], acc[i][j], 0, 0, 0);
        }
        __syncthreads();
    }
    // C/D layout: col = lane&15, row = quad*4 + reg  [m89/m91 verified]
#pragma unroll
    for (int i = 0; i < 4; ++i) {
        int rbase = r0 + wm * 64 + i * 16 + q * 4;
#pragma unroll
        for (int reg = 0; reg < 4; ++reg) {
            int r = rbase + reg;
            if (r < n) {
#pragma unroll
                for (int j = 0; j < 4; ++j) {
                    int c = c0 + wn * 64 + j * 16 + lm;
                    Z[(size_t)r * HD + c] = acc[i][j][reg];
                }
            }
        }
    }
}

// ---------------- heads MFMA: out[n,28] = A[n,512] @ Wh[32,512]^T + bias, routed ----
__global__ __launch_bounds__(128) void heads_mfma(const unsigned short* __restrict__ A,
                                                  const unsigned short* __restrict__ Wh,
                                                  const float* __restrict__ bcat,
                                                  float* __restrict__ out, int n) {
    __shared__ __align__(16) short As[128 * 64];
    __shared__ __align__(16) short Bs[32 * 64];
    int t = threadIdx.x;
    int wave = t >> 6, lane = t & 63;
    int lm = lane & 15, q = lane >> 4;
    int r0 = blockIdx.x * 128;

    f32x4 acc[4][2];
#pragma unroll
    for (int i = 0; i < 4; ++i)
#pragma unroll
        for (int j = 0; j < 2; ++j) acc[i][j] = (f32x4){0.f, 0.f, 0.f, 0.f};

    int srow = t >> 3;   // 0..15
    int skc = t & 7;

    for (int kt = 0; kt < 8; ++kt) {
        int kc = kt * 64;
#pragma unroll
        for (int u = 0; u < 8; ++u) {
            int row = srow + u * 16;
            int ga = r0 + row; if (ga >= n) ga = n - 1;
            *(float4*)&As[SWIZ(row, skc)] = *(const float4*)&A[(size_t)ga * KD + kc + skc * 8];
        }
#pragma unroll
        for (int u = 0; u < 2; ++u) {
            int c = t + u * 128;
            int row = c >> 3, kcc = c & 7;
            *(float4*)&Bs[SWIZ(row, kcc)] = *(const float4*)&Wh[(size_t)row * KD + kc + kcc * 8];
        }
        __syncthreads();
#pragma unroll
        for (int kk = 0; kk < 2; ++kk) {
            bf16x8 af[4], bfv[2];
#pragma unroll
            for (int i = 0; i < 4; ++i) {
                int row = wave * 64 + i * 16 + lm;
                af[i] = *(bf16x8*)&As[SWIZ(row, kk * 4 + q)];
            }
#pragma unroll
            for (int j = 0; j < 2; ++j) {
                int row = j * 16 + lm;
                bfv[j] = *(bf16x8*)&Bs[SWIZ(row, kk * 4 + q)];
            }
#pragma unroll
            for (int i = 0; i < 4; ++i)
#pragma unroll
                for (int j = 0; j < 2; ++j)
                    acc[i][j] = __builtin_amdgcn_mfma_f32_16x16x32_bf16(af[i], bfv[j], acc[i][j], 0, 0, 0);
        }
        __syncthreads();
    }
#pragma unroll
    for (int i = 0; i < 4; ++i) {
        int rbase = r0 + wave * 64 + i * 16 + q * 4;
#pragma unroll
        for (int reg = 0; reg < 4; ++reg) {
            int r = rbase + reg;
            if (r >= n) continue;
#pragma unroll
            for (int j = 0; j < 2; ++j) {
                int c = j * 16 + lm;
                if (c >= NH) continue;
                float v = acc[i][j][reg] + bcat[c];
                if (c < 21)      out[(size_t)r * 21 + c] = v;
                else if (c < 23) out[(size_t)n * 21 + (size_t)r * 2 + (c - 21)] = v;
                else             out[(size_t)n * 23 + (size_t)r * 5 + (c - 23)] = v;
            }
        }
    }
}

// ---------------- BN ----------------
__global__ void bn_stats_kernel(const float* __restrict__ Z, float* __restrict__ colsum,
                                float* __restrict__ colsumsq, int n) {
    int c = threadIdx.x;
    float s = 0.f, s2 = 0.f;
    for (int r = blockIdx.x; r < n; r += gridDim.x) {
        float v = Z[(size_t)r * HD + c];
        s += v; s2 += v * v;
    }
    atomicAdd(&colsum[c], s);
    atomicAdd(&colsumsq[c], s2);
}

__global__ void bn_finalize_kernel(const float* __restrict__ colsum, const float* __restrict__ colsumsq,
                                   const float* __restrict__ g, const float* __restrict__ bt,
                                   float* __restrict__ scale, float* __restrict__ shift, int n) {
    int c = threadIdx.x;
    float fn = (float)n;
    float mu = colsum[c] / fn;
    float var = colsumsq[c] / fn - mu * mu;
    float sc = g[c] / sqrtf(var + 1e-5f);
    scale[c] = sc;
    shift[c] = bt[c] - mu * sc;
}

// BN scale/shift + ReLU, write bf16 into right half of next [N][512] buffer
__global__ void bn_apply_relu_kernel(const float* __restrict__ Z, const float* __restrict__ scale,
                                     const float* __restrict__ shift, unsigned short* __restrict__ hout,
                                     int total4) {
    int idx = blockIdx.x * blockDim.x + threadIdx.x;
    if (idx >= total4) return;
    int r = idx >> 6, c4 = (idx & 63) * 4;
    float4 z = ((const float4*)Z)[idx];
    float4 sc = *(const float4*)&scale[c4];
    float4 sh = *(const float4*)&shift[c4];
    ushort4 o;
    o.x = f2bf(fmaxf(z.x * sc.x + sh.x, 0.f));
    o.y = f2bf(fmaxf(z.y * sc.y + sh.y, 0.f));
    o.z = f2bf(fmaxf(z.z * sc.z + sh.z, 0.f));
    o.w = f2bf(fmaxf(z.w * sc.w + sh.w, 0.f));
    *(ushort4*)&hout[(size_t)r * KD + HD + c4] = o;
}

// ---------------- host ----------------
static inline char* align256(char* p) {
    return (char*)(((uintptr_t)p + 255) & ~(uintptr_t)255);
}

extern "C" void kernel_launch(void* const* d_in, const int* in_sizes, int n_in,
                              void* d_out, int out_size, void* d_ws, size_t ws_size,
                              hipStream_t stream) {
    const float* x    = (const float*)d_in[0];
    const int*   esrc = (const int*)d_in[1];
    const int*   edst = (const int*)d_in[2];
    const float* w1l = (const float*)d_in[3];  const float* w1r = (const float*)d_in[5];
    const float* g1  = (const float*)d_in[6];  const float* bt1 = (const float*)d_in[7];
    const float* w2l = (const float*)d_in[8];  const float* w2r = (const float*)d_in[10];
    const float* g2  = (const float*)d_in[11]; const float* bt2 = (const float*)d_in[12];
    const float* w3l = (const float*)d_in[13]; const float* w3r = (const float*)d_in[15];
    const float* g3  = (const float*)d_in[16]; const float* bt3 = (const float*)d_in[17];
    const float* wal = (const float*)d_in[18]; const float* ba = (const float*)d_in[19];
    const float* war = (const float*)d_in[20];
    const float* wsl = (const float*)d_in[21]; const float* bs = (const float*)d_in[22];
    const float* wsr = (const float*)d_in[23];
    const float* wel = (const float*)d_in[24]; const float* be = (const float*)d_in[25];
    const float* wer = (const float*)d_in[26];
    float* out = (float*)d_out;

    int N = in_sizes[0] / HD;
    int E = in_sizes[1];

    char* p = (char*)d_ws;
    size_t HB = (size_t)N * KD * sizeof(unsigned short);   // [N][512] bf16
    unsigned short* buf0 = (unsigned short*)p; p += HB;
    unsigned short* buf1 = (unsigned short*)p; p += HB;
    p = align256(p);
    float* Z = (float*)p; p += (size_t)N * HD * sizeof(float);
    p = align256(p);
    int* col_idx = (int*)p; p += sizeof(int) * (size_t)E;       p = align256(p);
    int* row_ptr = (int*)p; p += sizeof(int) * (size_t)(N + 1); p = align256(p);
    int* cnt     = (int*)p; p += sizeof(int) * (size_t)N;       // cnt+cursor contiguous (one memset)
    int* cursor  = (int*)p; p += sizeof(int) * (size_t)N;       p = align256(p);
    int* bsum    = (int*)p; p += sizeof(int) * 256;
    int* boff    = (int*)p; p += sizeof(int) * 256;             p = align256(p);
    float* invdeg   = (float*)p; p += sizeof(float) * (size_t)N; p = align256(p);
    float* colsum   = (float*)p; p += sizeof(float) * 256;       // colsum+colsumsq contiguous
    float* colsumsq = (float*)p; p += sizeof(float) * 256;       p = align256(p);
    float* scale    = (float*)p; p += sizeof(float) * 256;
    float* shift    = (float*)p; p += sizeof(float) * 256;       p = align256(p);
    unsigned short* wc1 = (unsigned short*)p; p += sizeof(unsigned short) * HD * KD;
    unsigned short* wc2 = (unsigned short*)p; p += sizeof(unsigned short) * HD * KD;
    unsigned short* wc3 = (unsigned short*)p; p += sizeof(unsigned short) * HD * KD;
    unsigned short* wch = (unsigned short*)p; p += sizeof(unsigned short) * 32 * KD;
    p = align256(p);
    float* bcat = (float*)p; p += sizeof(float) * 32;
    (void)ws_size; (void)n_in; (void)out_size;

    int nchunks = (N + 255) / 256;

    // CSR build + weight packing
    hipMemsetAsync(cnt, 0, sizeof(int) * 2 * (size_t)N, stream);
    hist_kernel<<<(E + 255) / 256, 256, 0, stream>>>(edst, cnt, E);
    chunk_reduce_kernel<<<nchunks, 256, 0, stream>>>(cnt, bsum, N);
    scan_chunks_kernel<<<1, 256, 0, stream>>>(bsum, boff, nchunks, &row_ptr[N], E);
    scan_final_kernel<<<nchunks, 256, 0, stream>>>(cnt, boff, row_ptr, invdeg, N);
    scatter_kernel<<<(E + 255) / 256, 256, 0, stream>>>(esrc, edst, row_ptr, cursor, col_idx, E);
    pack_layer_w<<<(HD * KD + 255) / 256, 256, 0, stream>>>(w1l, w1r, wc1);
    pack_layer_w<<<(HD * KD + 255) / 256, 256, 0, stream>>>(w2l, w2r, wc2);
    pack_layer_w<<<(HD * KD + 255) / 256, 256, 0, stream>>>(w3l, w3r, wc3);
    pack_heads<<<(32 * KD + 255) / 256, 256, 0, stream>>>(wal, war, wsl, wsr, wel, wer,
                                                          ba, bs, be, wch, bcat);
    convert_x_kernel<<<(N * 64 + 255) / 256, 256, 0, stream>>>(x, buf0, N);

    int aggGrid = (N + 3) / 4;
    dim3 gemmGrid((N + 127) / 128, 2);
    int total4 = N * 64;

    unsigned short* cur = buf0;
    unsigned short* nxt = buf1;
    const unsigned short* wcs[3] = {wc1, wc2, wc3};
    const float* gs[3]  = {g1, g2, g3};
    const float* bts[3] = {bt1, bt2, bt3};

    for (int l = 0; l < 3; ++l) {
        // mean-aggregate cur's self features into cur's left half
        agg_mean_bf16<<<aggGrid, 256, 0, stream>>>(cur, row_ptr, col_idx, invdeg, N);
        // Z = [mean|self] @ Wcat^T   (layer bias omitted: exactly cancelled by batch-stat BN)
        gemm_mfma<<<gemmGrid, 256, 0, stream>>>(cur, wcs[l], Z, N);
        hipMemsetAsync(colsum, 0, sizeof(float) * 512, stream);
        bn_stats_kernel<<<400, 256, 0, stream>>>(Z, colsum, colsumsq, N);
        bn_finalize_kernel<<<1, 256, 0, stream>>>(colsum, colsumsq, gs[l], bts[l], scale, shift, N);
        bn_apply_relu_kernel<<<(total4 + 255) / 256, 256, 0, stream>>>(Z, scale, shift, nxt, total4);
        unsigned short* t2 = cur; cur = nxt; nxt = t2;
    }

    // heads: shared aggregation of h3, then fused 28-col MFMA GEMM (bias included)
    agg_mean_bf16<<<aggGrid, 256, 0, stream>>>(cur, row_ptr, col_idx, invdeg, N);
    heads_mfma<<<(N + 127) / 128, 128, 0, stream>>>(cur, wch, bcat, out, N);
}

// Round 3
// 571.433 us; speedup vs baseline: 2.8852x; 1.2805x over previous
//
#include <hip/hip_runtime.h>
#include <hip/hip_bf16.h>
#include <cstddef>

#define HD 256   // hidden dim
#define KD 512   // concat K (mean | self)
#define NH 28    // total head outputs (21+2+5)

typedef __attribute__((ext_vector_type(8))) short bf16x8;
typedef __attribute__((ext_vector_type(4))) float f32x4;

__device__ inline float bf2f(unsigned short u) { return __uint_as_float(((unsigned)u) << 16); }
__device__ inline unsigned short f2bf(float f) {
    __hip_bfloat16 h = __float2bfloat16(f);
    return *(unsigned short*)&h;
}

// ---------------- CSR build ----------------
__global__ void hist_kernel(const int* __restrict__ dst, int* __restrict__ cnt, int E) {
    int e = blockIdx.x * blockDim.x + threadIdx.x;
    if (e < E) atomicAdd(&cnt[dst[e]], 1);
}

__global__ void chunk_reduce_kernel(const int* __restrict__ cnt, int* __restrict__ bsum, int n) {
    __shared__ int sdata[4];
    int idx = blockIdx.x * 256 + threadIdx.x;
    int v = (idx < n) ? cnt[idx] : 0;
    for (int off = 32; off > 0; off >>= 1) v += __shfl_down(v, off, 64);
    int lane = threadIdx.x & 63, wv = threadIdx.x >> 6;
    if (lane == 0) sdata[wv] = v;
    __syncthreads();
    if (threadIdx.x == 0) bsum[blockIdx.x] = sdata[0] + sdata[1] + sdata[2] + sdata[3];
}

__global__ void scan_chunks_kernel(const int* __restrict__ bsum, int* __restrict__ boff,
                                   int nchunks, int* __restrict__ row_ptr_end, int E) {
    int t = threadIdx.x;
    int v = (t < nchunks) ? bsum[t] : 0;
    int lane = t & 63, wv = t >> 6;
    int incl = v;
    for (int off = 1; off < 64; off <<= 1) { int u = __shfl_up(incl, off, 64); if (lane >= off) incl += u; }
    __shared__ int wsum[4];
    if (lane == 63) wsum[wv] = incl;
    __syncthreads();
    int base = 0;
    for (int w2 = 0; w2 < 4; ++w2) if (w2 < wv) base += wsum[w2];
    if (t < nchunks) boff[t] = base + incl - v;
    if (t == 0) *row_ptr_end = E;
}

__global__ void scan_final_kernel(const int* __restrict__ cnt, const int* __restrict__ boff,
                                  int* __restrict__ row_ptr, float* __restrict__ invdeg, int n) {
    int idx = blockIdx.x * 256 + threadIdx.x;
    int v = (idx < n) ? cnt[idx] : 0;
    int lane = threadIdx.x & 63, wv = threadIdx.x >> 6;
    int incl = v;
    for (int off = 1; off < 64; off <<= 1) { int u = __shfl_up(incl, off, 64); if (lane >= off) incl += u; }
    __shared__ int wsum[4];
    if (lane == 63) wsum[wv] = incl;
    __syncthreads();
    int base = 0;
    for (int w2 = 0; w2 < 4; ++w2) if (w2 < wv) base += wsum[w2];
    if (idx < n) {
        row_ptr[idx] = boff[blockIdx.x] + base + incl - v;
        invdeg[idx] = 1.0f / fmaxf((float)v, 1.0f);
    }
}

__global__ void scatter_kernel(const int* __restrict__ src, const int* __restrict__ dst,
                               const int* __restrict__ row_ptr, int* __restrict__ cursor,
                               int* __restrict__ col_idx, int E) {
    int e = blockIdx.x * blockDim.x + threadIdx.x;
    if (e < E) {
        int d = dst[e];
        int pos = atomicAdd(&cursor[d], 1);
        col_idx[row_ptr[d] + pos] = src[e];
    }
}

// ---------------- weight packing ----------------
__global__ void pack_layer_w(const float* __restrict__ wl, const float* __restrict__ wr,
                             unsigned short* __restrict__ dst) {
    int idx = blockIdx.x * 256 + threadIdx.x;   // 256*512 total
    if (idx >= HD * KD) return;
    int nn = idx >> 9, k = idx & 511;
    float v = (k < HD) ? wl[nn * HD + k] : wr[nn * HD + (k - HD)];
    dst[idx] = f2bf(v);
}

// W2[64][256]: rows 0..27 = L heads, rows 32..59 = R heads, rest zero
__global__ void pack_heads2(const float* __restrict__ wal, const float* __restrict__ war,
                            const float* __restrict__ wsl, const float* __restrict__ wsr,
                            const float* __restrict__ wel, const float* __restrict__ wer,
                            const float* __restrict__ ba, const float* __restrict__ bs,
                            const float* __restrict__ be,
                            unsigned short* __restrict__ W2, float* __restrict__ bcat) {
    int idx = blockIdx.x * 256 + threadIdx.x;   // 64*256 total
    if (idx >= 64 * HD) return;
    int o = idx >> 8, k = idx & 255;
    float v = 0.f;
    if (o < 21)                    v = wal[o * HD + k];
    else if (o < 23)               v = wsl[(o - 21) * HD + k];
    else if (o < 28)               v = wel[(o - 23) * HD + k];
    else if (o >= 32 && o < 53)    v = war[(o - 32) * HD + k];
    else if (o >= 53 && o < 55)    v = wsr[(o - 53) * HD + k];
    else if (o >= 55 && o < 60)    v = wer[(o - 55) * HD + k];
    W2[idx] = f2bf(v);
    if (k == 0 && o < 32) {
        float b = 0.f;
        if (o < 21) b = ba[o]; else if (o < 23) b = bs[o - 21]; else if (o < 28) b = be[o - 23];
        bcat[o] = b;
    }
}

// x fp32 -> bf16 into right half of [N][512] buffer
__global__ void convert_x_kernel(const float* __restrict__ x, unsigned short* __restrict__ buf, int n) {
    int idx = blockIdx.x * 256 + threadIdx.x;   // n*64
    if (idx >= n * 64) return;
    int r = idx >> 6, c4 = (idx & 63) * 4;
    float4 v = ((const float4*)x)[idx];
    ushort4 o;
    o.x = f2bf(v.x); o.y = f2bf(v.y); o.z = f2bf(v.z); o.w = f2bf(v.w);
    *(ushort4*)&buf[(size_t)r * KD + HD + c4] = o;
}

// ---------------- mean aggregation: 2 nodes per wave, 32 lanes x 16B each ----------------
__global__ void agg_mean_bf16(unsigned short* __restrict__ buf,
                              const int* __restrict__ row_ptr, const int* __restrict__ col_idx,
                              const float* __restrict__ invdeg, int n) {
    int half = threadIdx.x >> 5;      // 0..7
    int l32 = threadIdx.x & 31;
    int node = blockIdx.x * 8 + half;
    if (node >= n) return;
    int s = row_ptr[node], e = row_ptr[node + 1];
    int coff = HD + l32 * 8;          // right-half, 8 bf16 per lane
    float a[8];
#pragma unroll
    for (int k = 0; k < 8; ++k) a[k] = 0.f;
    int i = s;
    for (; i + 4 <= e; i += 4) {
        int s0 = col_idx[i], s1 = col_idx[i + 1], s2 = col_idx[i + 2], s3 = col_idx[i + 3];
        float4 v0 = *(const float4*)&buf[(size_t)s0 * KD + coff];
        float4 v1 = *(const float4*)&buf[(size_t)s1 * KD + coff];
        float4 v2 = *(const float4*)&buf[(size_t)s2 * KD + coff];
        float4 v3 = *(const float4*)&buf[(size_t)s3 * KD + coff];
        const unsigned short* u0 = (const unsigned short*)&v0;
        const unsigned short* u1 = (const unsigned short*)&v1;
        const unsigned short* u2 = (const unsigned short*)&v2;
        const unsigned short* u3 = (const unsigned short*)&v3;
#pragma unroll
        for (int k = 0; k < 8; ++k) a[k] += bf2f(u0[k]) + bf2f(u1[k]) + bf2f(u2[k]) + bf2f(u3[k]);
    }
    for (; i < e; ++i) {
        int s0 = col_idx[i];
        float4 v = *(const float4*)&buf[(size_t)s0 * KD + coff];
        const unsigned short* u = (const unsigned short*)&v;
#pragma unroll
        for (int k = 0; k < 8; ++k) a[k] += bf2f(u[k]);
    }
    float inv = invdeg[node];
    ushort4 o0, o1;
    o0.x = f2bf(a[0] * inv); o0.y = f2bf(a[1] * inv); o0.z = f2bf(a[2] * inv); o0.w = f2bf(a[3] * inv);
    o1.x = f2bf(a[4] * inv); o1.y = f2bf(a[5] * inv); o1.z = f2bf(a[6] * inv); o1.w = f2bf(a[7] * inv);
    *(ushort4*)&buf[(size_t)node * KD + l32 * 8] = o0;
    *(ushort4*)&buf[(size_t)node * KD + l32 * 8 + 4] = o1;
}

// ---------------- MFMA GEMM + fused BN stats ----------------
// Z[n,256] = A[n,512](bf16) @ W[256,512]^T (bf16); writes bf16 into nxt right half;
// atomically accumulates per-column sum/sumsq from fp32 accumulators.
// 512 threads = 8 waves (2 row-halves x 4 col-quarters), 128x256 tile, BK=64.
#define SWIZ(row, kc) (((row) << 6) + ((((kc) ^ ((row) & 7))) << 3))

__global__ __launch_bounds__(512) void gemm_mfma_stats(
        const unsigned short* __restrict__ A, const unsigned short* __restrict__ W,
        unsigned short* __restrict__ Zb,   // next-layer buffer base; write to right half
        float* __restrict__ colsum, float* __restrict__ colsumsq, int n) {
    __shared__ __align__(16) short As[128 * 64];
    __shared__ __align__(16) short Bs[256 * 64];
    int t = threadIdx.x;
    int wave = t >> 6, lane = t & 63;
    int wm = wave & 1, wn = wave >> 1;          // wm: row half, wn: col quarter
    int lm = lane & 15, q = lane >> 4;
    int r0 = blockIdx.x * 128;

    f32x4 acc[4][4];
#pragma unroll
    for (int i = 0; i < 4; ++i)
#pragma unroll
        for (int j = 0; j < 4; ++j) acc[i][j] = (f32x4){0.f, 0.f, 0.f, 0.f};

    int srow = t >> 3;     // 0..63
    int skc = t & 7;

    for (int kt = 0; kt < 8; ++kt) {
        int kc = kt * 64;
#pragma unroll
        for (int u = 0; u < 2; ++u) {           // A: 128 rows
            int row = srow + u * 64;
            int ga = r0 + row; if (ga >= n) ga = n - 1;
            *(float4*)&As[SWIZ(row, skc)] = *(const float4*)&A[(size_t)ga * KD + kc + skc * 8];
        }
#pragma unroll
        for (int u = 0; u < 4; ++u) {           // W: 256 rows
            int row = srow + u * 64;
            *(float4*)&Bs[SWIZ(row, skc)] = *(const float4*)&W[(size_t)row * KD + kc + skc * 8];
        }
        __syncthreads();
#pragma unroll
        for (int kk = 0; kk < 2; ++kk) {
            bf16x8 af[4], bfv[4];
#pragma unroll
            for (int i = 0; i < 4; ++i)
                af[i] = *(bf16x8*)&As[SWIZ(wm * 64 + i * 16 + lm, kk * 4 + q)];
#pragma unroll
            for (int j = 0; j < 4; ++j)
                bfv[j] = *(bf16x8*)&Bs[SWIZ(wn * 64 + j * 16 + lm, kk * 4 + q)];
#pragma unroll
            for (int i = 0; i < 4; ++i)
#pragma unroll
                for (int j = 0; j < 4; ++j)
                    acc[i][j] = __builtin_amdgcn_mfma_f32_16x16x32_bf16(af[i], bfv[j], acc[i][j], 0, 0, 0);
        }
        __syncthreads();
    }

    // epilogue: write Z bf16 + per-column stats
    // C/D layout: col = lane&15, row = q*4 + reg  [m89/m91 verified]
    float s[4], s2[4];
#pragma unroll
    for (int j = 0; j < 4; ++j) { s[j] = 0.f; s2[j] = 0.f; }
#pragma unroll
    for (int i = 0; i < 4; ++i) {
        int rbase = r0 + wm * 64 + i * 16 + q * 4;
#pragma unroll
        for (int reg = 0; reg < 4; ++reg) {
            int r = rbase + reg;
            if (r < n) {
#pragma unroll
                for (int j = 0; j < 4; ++j) {
                    float v = acc[i][j][reg];
                    int c = wn * 64 + j * 16 + lm;
                    Zb[(size_t)r * KD + HD + c] = f2bf(v);
                    s[j] += v; s2[j] += v * v;
                }
            }
        }
    }
#pragma unroll
    for (int j = 0; j < 4; ++j) {
        s[j]  += __shfl_xor(s[j], 16, 64);  s[j]  += __shfl_xor(s[j], 32, 64);
        s2[j] += __shfl_xor(s2[j], 16, 64); s2[j] += __shfl_xor(s2[j], 32, 64);
    }
    if (lane < 16) {
#pragma unroll
        for (int j = 0; j < 4; ++j) {
            int c = wn * 64 + j * 16 + lm;
            atomicAdd(&colsum[c], s[j]);
            atomicAdd(&colsumsq[c], s2[j]);
        }
    }
}

// ---------------- BN ----------------
__global__ void bn_finalize_kernel(const float* __restrict__ colsum, const float* __restrict__ colsumsq,
                                   const float* __restrict__ g, const float* __restrict__ bt,
                                   float* __restrict__ scale, float* __restrict__ shift, int n) {
    int c = threadIdx.x;
    float fn = (float)n;
    float mu = colsum[c] / fn;
    float var = colsumsq[c] / fn - mu * mu;
    float sc = g[c] / sqrtf(var + 1e-5f);
    scale[c] = sc;
    shift[c] = bt[c] - mu * sc;
}

// in-place BN+ReLU on the right half of buf (bf16)
__global__ void bn_apply_relu_kernel(unsigned short* __restrict__ buf, const float* __restrict__ scale,
                                     const float* __restrict__ shift, int total4) {
    int idx = blockIdx.x * blockDim.x + threadIdx.x;
    if (idx >= total4) return;
    int r = idx >> 6, c4 = (idx & 63) * 4;
    unsigned short* p = &buf[(size_t)r * KD + HD + c4];
    ushort4 z = *(ushort4*)p;
    float4 sc = *(const float4*)&scale[c4];
    float4 sh = *(const float4*)&shift[c4];
    ushort4 o;
    o.x = f2bf(fmaxf(bf2f(z.x) * sc.x + sh.x, 0.f));
    o.y = f2bf(fmaxf(bf2f(z.y) * sc.y + sh.y, 0.f));
    o.z = f2bf(fmaxf(bf2f(z.z) * sc.z + sh.z, 0.f));
    o.w = f2bf(fmaxf(bf2f(z.w) * sc.w + sh.w, 0.f));
    *(ushort4*)p = o;
}

// ---------------- heads: P = h3 @ W2^T  (PL = L-heads, PR = R-heads) ----------------
// A = cur self half (stride KD), K=256. Output PL[N][32], PR[N][32] bf16.
__global__ __launch_bounds__(256) void heads_pgemm(const unsigned short* __restrict__ A,
                                                   const unsigned short* __restrict__ W2,
                                                   unsigned short* __restrict__ PL,
                                                   unsigned short* __restrict__ PR, int n) {
    __shared__ __align__(16) short As[128 * 64];
    __shared__ __align__(16) short Bs[64 * 64];
    int t = threadIdx.x;
    int wave = t >> 6, lane = t & 63;
    int lm = lane & 15, q = lane >> 4;
    int r0 = blockIdx.x * 128;

    f32x4 acc[2][4];
#pragma unroll
    for (int i = 0; i < 2; ++i)
#pragma unroll
        for (int j = 0; j < 4; ++j) acc[i][j] = (f32x4){0.f, 0.f, 0.f, 0.f};

    int srow = t >> 3;   // 0..31
    int skc = t & 7;

    for (int kt = 0; kt < 4; ++kt) {
        int kc = kt * 64;
#pragma unroll
        for (int u = 0; u < 4; ++u) {
            int row = srow + u * 32;
            int ga = r0 + row; if (ga >= n) ga = n - 1;
            *(float4*)&As[SWIZ(row, skc)] = *(const float4*)&A[(size_t)ga * KD + kc + skc * 8];
        }
#pragma unroll
        for (int u = 0; u < 2; ++u) {
            int c = t + u * 256;
            int row = c >> 3, kcc = c & 7;
            *(float4*)&Bs[SWIZ(row, kcc)] = *(const float4*)&W2[(size_t)row * HD + kc + kcc * 8];
        }
        __syncthreads();
#pragma unroll
        for (int kk = 0; kk < 2; ++kk) {
            bf16x8 af[2], bfv[4];
#pragma unroll
            for (int i = 0; i < 2; ++i)
                af[i] = *(bf16x8*)&As[SWIZ(wave * 32 + i * 16 + lm, kk * 4 + q)];
#pragma unroll
            for (int j = 0; j < 4; ++j)
                bfv[j] = *(bf16x8*)&Bs[SWIZ(j * 16 + lm, kk * 4 + q)];
#pragma unroll
            for (int i = 0; i < 2; ++i)
#pragma unroll
                for (int j = 0; j < 4; ++j)
                    acc[i][j] = __builtin_amdgcn_mfma_f32_16x16x32_bf16(af[i], bfv[j], acc[i][j], 0, 0, 0);
        }
        __syncthreads();
    }
#pragma unroll
    for (int i = 0; i < 2; ++i) {
        int rbase = r0 + wave * 32 + i * 16 + q * 4;
#pragma unroll
        for (int reg = 0; reg < 4; ++reg) {
            int r = rbase + reg;
            if (r >= n) continue;
#pragma unroll
            for (int j = 0; j < 4; ++j) {
                int c = j * 16 + lm;
                unsigned short v = f2bf(acc[i][j][reg]);
                if (c < 32) PL[(size_t)r * 32 + c] = v;
                else        PR[(size_t)r * 32 + (c - 32)] = v;
            }
        }
    }
}

// out = S@PL + PR + bias, routed. 4 nodes per wave (16 lanes x 2 cols each).
__global__ void head_agg(const unsigned short* __restrict__ PL, const unsigned short* __restrict__ PR,
                         const int* __restrict__ row_ptr, const int* __restrict__ col_idx,
                         const float* __restrict__ invdeg, const float* __restrict__ bcat,
                         float* __restrict__ out, int n) {
    int t = threadIdx.x;
    int sub = t >> 4;          // 0..15
    int l16 = t & 15;
    int node = blockIdx.x * 16 + sub;
    if (node >= n) return;
    int s = row_ptr[node], e = row_ptr[node + 1];
    int off = l16 * 2;
    float a0 = 0.f, a1 = 0.f;
    int i = s;
    for (; i + 4 <= e; i += 4) {
        int s0 = col_idx[i], s1 = col_idx[i + 1], s2 = col_idx[i + 2], s3 = col_idx[i + 3];
        unsigned v0 = *(const unsigned*)&PL[(size_t)s0 * 32 + off];
        unsigned v1 = *(const unsigned*)&PL[(size_t)s1 * 32 + off];
        unsigned v2 = *(const unsigned*)&PL[(size_t)s2 * 32 + off];
        unsigned v3 = *(const unsigned*)&PL[(size_t)s3 * 32 + off];
        a0 += bf2f((unsigned short)v0) + bf2f((unsigned short)v1) + bf2f((unsigned short)v2) + bf2f((unsigned short)v3);
        a1 += bf2f((unsigned short)(v0 >> 16)) + bf2f((unsigned short)(v1 >> 16))
            + bf2f((unsigned short)(v2 >> 16)) + bf2f((unsigned short)(v3 >> 16));
    }
    for (; i < e; ++i) {
        unsigned v = *(const unsigned*)&PL[(size_t)col_idx[i] * 32 + off];
        a0 += bf2f((unsigned short)v);
        a1 += bf2f((unsigned short)(v >> 16));
    }
    float inv = invdeg[node];
    unsigned vr = *(const unsigned*)&PR[(size_t)node * 32 + off];
    float o0 = a0 * inv + bf2f((unsigned short)vr) + bcat[off];
    float o1 = a1 * inv + bf2f((unsigned short)(vr >> 16)) + bcat[off + 1];
    int c0 = off, c1 = off + 1;
    if (c0 < 21)      out[(size_t)node * 21 + c0] = o0;
    else if (c0 < 23) out[(size_t)n * 21 + (size_t)node * 2 + (c0 - 21)] = o0;
    else if (c0 < 28) out[(size_t)n * 23 + (size_t)node * 5 + (c0 - 23)] = o0;
    if (c1 < 21)      out[(size_t)node * 21 + c1] = o1;
    else if (c1 < 23) out[(size_t)n * 21 + (size_t)node * 2 + (c1 - 21)] = o1;
    else if (c1 < 28) out[(size_t)n * 23 + (size_t)node * 5 + (c1 - 23)] = o1;
}

// ---------------- host ----------------
static inline char* align256(char* p) {
    return (char*)(((uintptr_t)p + 255) & ~(uintptr_t)255);
}

extern "C" void kernel_launch(void* const* d_in, const int* in_sizes, int n_in,
                              void* d_out, int out_size, void* d_ws, size_t ws_size,
                              hipStream_t stream) {
    const float* x    = (const float*)d_in[0];
    const int*   esrc = (const int*)d_in[1];
    const int*   edst = (const int*)d_in[2];
    const float* w1l = (const float*)d_in[3];  const float* w1r = (const float*)d_in[5];
    const float* g1  = (const float*)d_in[6];  const float* bt1 = (const float*)d_in[7];
    const float* w2l = (const float*)d_in[8];  const float* w2r = (const float*)d_in[10];
    const float* g2  = (const float*)d_in[11]; const float* bt2 = (const float*)d_in[12];
    const float* w3l = (const float*)d_in[13]; const float* w3r = (const float*)d_in[15];
    const float* g3  = (const float*)d_in[16]; const float* bt3 = (const float*)d_in[17];
    const float* wal = (const float*)d_in[18]; const float* ba = (const float*)d_in[19];
    const float* war = (const float*)d_in[20];
    const float* wsl = (const float*)d_in[21]; const float* bs = (const float*)d_in[22];
    const float* wsr = (const float*)d_in[23];
    const float* wel = (const float*)d_in[24]; const float* be = (const float*)d_in[25];
    const float* wer = (const float*)d_in[26];
    float* out = (float*)d_out;

    int N = in_sizes[0] / HD;
    int E = in_sizes[1];

    char* p = (char*)d_ws;
    size_t HB = (size_t)N * KD * sizeof(unsigned short);   // [N][512] bf16
    unsigned short* buf0 = (unsigned short*)p; p += HB;
    unsigned short* buf1 = (unsigned short*)p; p += HB;
    p = align256(p);
    unsigned short* PLb = (unsigned short*)p; p += (size_t)N * 32 * sizeof(unsigned short);
    unsigned short* PRb = (unsigned short*)p; p += (size_t)N * 32 * sizeof(unsigned short);
    p = align256(p);
    int* col_idx = (int*)p; p += sizeof(int) * (size_t)E;       p = align256(p);
    int* row_ptr = (int*)p; p += sizeof(int) * (size_t)(N + 1); p = align256(p);
    int* cnt     = (int*)p; p += sizeof(int) * (size_t)N;       // cnt+cursor contiguous (one memset)
    int* cursor  = (int*)p; p += sizeof(int) * (size_t)N;       p = align256(p);
    int* bsum    = (int*)p; p += sizeof(int) * 256;
    int* boff    = (int*)p; p += sizeof(int) * 256;             p = align256(p);
    float* invdeg   = (float*)p; p += sizeof(float) * (size_t)N; p = align256(p);
    float* colsum   = (float*)p; p += sizeof(float) * 256;       // colsum+colsumsq contiguous
    float* colsumsq = (float*)p; p += sizeof(float) * 256;       p = align256(p);
    float* scale    = (float*)p; p += sizeof(float) * 256;
    float* shift    = (float*)p; p += sizeof(float) * 256;       p = align256(p);
    unsigned short* wc1 = (unsigned short*)p; p += sizeof(unsigned short) * HD * KD;
    unsigned short* wc2 = (unsigned short*)p; p += sizeof(unsigned short) * HD * KD;
    unsigned short* wc3 = (unsigned short*)p; p += sizeof(unsigned short) * HD * KD;
    unsigned short* w2h = (unsigned short*)p; p += sizeof(unsigned short) * 64 * HD;
    p = align256(p);
    float* bcat = (float*)p; p += sizeof(float) * 32;
    (void)ws_size; (void)n_in; (void)out_size;

    int nchunks = (N + 255) / 256;

    // CSR build + weight packing
    hipMemsetAsync(cnt, 0, sizeof(int) * 2 * (size_t)N, stream);
    hist_kernel<<<(E + 255) / 256, 256, 0, stream>>>(edst, cnt, E);
    chunk_reduce_kernel<<<nchunks, 256, 0, stream>>>(cnt, bsum, N);
    scan_chunks_kernel<<<1, 256, 0, stream>>>(bsum, boff, nchunks, &row_ptr[N], E);
    scan_final_kernel<<<nchunks, 256, 0, stream>>>(cnt, boff, row_ptr, invdeg, N);
    scatter_kernel<<<(E + 255) / 256, 256, 0, stream>>>(esrc, edst, row_ptr, cursor, col_idx, E);
    pack_layer_w<<<(HD * KD + 255) / 256, 256, 0, stream>>>(w1l, w1r, wc1);
    pack_layer_w<<<(HD * KD + 255) / 256, 256, 0, stream>>>(w2l, w2r, wc2);
    pack_layer_w<<<(HD * KD + 255) / 256, 256, 0, stream>>>(w3l, w3r, wc3);
    pack_heads2<<<(64 * HD + 255) / 256, 256, 0, stream>>>(wal, war, wsl, wsr, wel, wer,
                                                           ba, bs, be, w2h, bcat);
    convert_x_kernel<<<(N * 64 + 255) / 256, 256, 0, stream>>>(x, buf0, N);

    int aggGrid = (N + 7) / 8;
    int gemmGrid = (N + 127) / 128;
    int total4 = N * 64;

    unsigned short* cur = buf0;
    unsigned short* nxt = buf1;
    const unsigned short* wcs[3] = {wc1, wc2, wc3};
    const float* gs[3]  = {g1, g2, g3};
    const float* bts[3] = {bt1, bt2, bt3};

    for (int l = 0; l < 3; ++l) {
        // mean-aggregate cur's self features into cur's left half
        agg_mean_bf16<<<aggGrid, 256, 0, stream>>>(cur, row_ptr, col_idx, invdeg, N);
        hipMemsetAsync(colsum, 0, sizeof(float) * 512, stream);
        // Z = [mean|self] @ Wcat^T  -> bf16 into nxt right half, + fused BN stats
        // (layer bias omitted: exactly cancelled by batch-stat BN)
        gemm_mfma_stats<<<gemmGrid, 512, 0, stream>>>(cur, wcs[l], nxt, colsum, colsumsq, N);
        bn_finalize_kernel<<<1, 256, 0, stream>>>(colsum, colsumsq, gs[l], bts[l], scale, shift, N);
        bn_apply_relu_kernel<<<(total4 + 255) / 256, 256, 0, stream>>>(nxt, scale, shift, total4);
        unsigned short* t2 = cur; cur = nxt; nxt = t2;
    }

    // heads: P = h3 @ [L|R]^T (K=256), then 28-wide aggregation (L2-resident gather)
    heads_pgemm<<<gemmGrid, 256, 0, stream>>>(cur + HD, w2h, PLb, PRb, N);
    head_agg<<<(N + 15) / 16, 256, 0, stream>>>(PLb, PRb, row_ptr, col_idx, invdeg, bcat, out, N);
}